// Round 13
// baseline (76.104 us; speedup 1.0000x reference)
//
#include <hip/hip_runtime.h>
#include <math.h>

typedef unsigned short u16;
typedef u16 u16x4 __attribute__((ext_vector_type(4)));
typedef u16 u16x8 __attribute__((ext_vector_type(8)));
typedef float f32x4 __attribute__((ext_vector_type(4)));
typedef float f32x16 __attribute__((ext_vector_type(16)));
typedef __bf16 bf16x8 __attribute__((ext_vector_type(8)));

#define KC 8
#define K2L 2304  // 256*9

__device__ __forceinline__ u16 f2bf_rne(float f) {
  unsigned u = __float_as_uint(f);
  u += 0x7FFFu + ((u >> 16) & 1u);
  return (u16)(u >> 16);
}
__device__ __forceinline__ float bf2f(u16 h) {
  return __uint_as_float(((unsigned)h) << 16);
}

// async global->LDS, 16B/lane; LDS dest is the WAVE-UNIFORM base (HW adds lane*16)
__device__ __forceinline__ void gload16(const u16* g, u16* l) {
  __builtin_amdgcn_global_load_lds(
      (const __attribute__((address_space(1))) unsigned*)g,
      (__attribute__((address_space(3))) unsigned*)l, 16, 0, 0);
}
template <int N>
__device__ __forceinline__ void vmwait() {
  if constexpr (N == 0)      asm volatile("s_waitcnt vmcnt(0)" ::: "memory");
  else if constexpr (N == 3) asm volatile("s_waitcnt vmcnt(3)" ::: "memory");
  else static_assert(N == 0, "unsupported vmcnt literal");
}

// ---- merged prep: split x, split W1, build Wc1, Wc2 ----
__device__ __forceinline__ void split4(const float* X, u16* hi, u16* lo, int i) {
  f32x4 v = ((const f32x4*)X)[i];
  u16x4 h, l;
#pragma unroll
  for (int c = 0; c < 4; ++c) {
    u16 hb = f2bf_rne(v[c]);
    h[c] = hb;
    l[c] = f2bf_rne(v[c] - bf2f(hb));
  }
  ((u16x4*)hi)[i] = h;
  ((u16x4*)lo)[i] = l;
}
__device__ __forceinline__ void wc_one(const float* coef, const float* sb, const float* sp,
                                       const float* mask, u16* W, int N, int idx) {
  int o = idx / K2L;
  int r = idx - o * K2L;
  int i = r / 9;
  int c = r - i * 9;
  int io = i * N + o;
  float m = mask[io];
  float v = (c == 0) ? m * sb[io] : m * sp[io] * coef[(size_t)io * KC + (c - 1)];
  W[idx] = f2bf_rne(v);
}

__global__ void prep_kernel(const float* __restrict__ x, const float* __restrict__ W1,
                            const float* __restrict__ coef1, const float* __restrict__ sb1,
                            const float* __restrict__ sp1, const float* __restrict__ mask1,
                            const float* __restrict__ coef2, const float* __restrict__ sb2,
                            const float* __restrict__ sp2, const float* __restrict__ mask2,
                            u16* __restrict__ xs_hi, u16* __restrict__ xs_lo,
                            u16* __restrict__ w1_hi, u16* __restrict__ w1_lo,
                            u16* __restrict__ wc1, u16* __restrict__ wc2) {
  const int b = blockIdx.x, tid = threadIdx.x;
  if (b < 4096) {
    split4(x, xs_hi, xs_lo, b * 256 + tid);
  } else if (b < 4096 + 256) {
    split4(W1, w1_hi, w1_lo, (b - 4096) * 256 + tid);
  } else if (b < 4096 + 256 + 2304) {
    wc_one(coef1, sb1, sp1, mask1, wc1, 256, (b - 4352) * 256 + tid);
  } else {
    wc_one(coef2, sb2, sp2, mask2, wc2, 128, (b - 6656) * 256 + tid);
  }
}

// ---- spline tables + divide-free expand ----
struct Spl {
  float g[12];
  float d1[11], d2[10], d3[9];
};
__device__ __forceinline__ void spl_init(const float* __restrict__ grid, Spl& sp) {
#pragma unroll
  for (int j = 0; j < 12; ++j) sp.g[j] = grid[j];
#pragma unroll
  for (int j = 0; j < 11; ++j) sp.d1[j] = 1.0f / (sp.g[j + 1] - sp.g[j]);
#pragma unroll
  for (int j = 0; j < 10; ++j) sp.d2[j] = 1.0f / (sp.g[j + 2] - sp.g[j]);
#pragma unroll
  for (int j = 0; j < 9; ++j) sp.d3[j] = 1.0f / (sp.g[j + 3] - sp.g[j]);
}
__device__ __forceinline__ void expand_one(float v, const Spl& sp, u16* dst) {
  float Bv[11];
#pragma unroll
  for (int j = 0; j < 11; ++j) Bv[j] = (v >= sp.g[j] && v < sp.g[j + 1]) ? 1.0f : 0.0f;
#pragma unroll
  for (int j = 0; j < 10; ++j)
    Bv[j] = (v - sp.g[j]) * sp.d1[j] * Bv[j] + (sp.g[j + 2] - v) * sp.d1[j + 1] * Bv[j + 1];
#pragma unroll
  for (int j = 0; j < 9; ++j)
    Bv[j] = (v - sp.g[j]) * sp.d2[j] * Bv[j] + (sp.g[j + 3] - v) * sp.d2[j + 1] * Bv[j + 1];
#pragma unroll
  for (int j = 0; j < 8; ++j)
    Bv[j] = (v - sp.g[j]) * sp.d3[j] * Bv[j] + (sp.g[j + 4] - v) * sp.d3[j + 1] * Bv[j + 1];
  dst[0] = f2bf_rne(v / (1.0f + __expf(-v)));  // silu
#pragma unroll
  for (int k = 0; k < 8; ++k) dst[1 + k] = f2bf_rne(Bv[k]);
}

// ---- 8-wave MFMA GEMM, small-tile / 2-blocks-per-CU variant ----
// BM=MQ*32, BN=NQ*32 (MQ*NQ=2), BK=128.  8 waves = MQ x NQ quadrants x 4 kg
// (kg owns 2 of the 8 K-16 slices).  3-buf ring (72 KB LDS -> 2 blocks/CU),
// depth-2 prefetch, counted vmcnt, ONE s_barrier/step, stage AFTER barrier
// (3-buf safety: buf (i+2)%3's readers ran at step i-1, pre-barrier-i).
// Staging: linear LDS dest + inverse-swizzled global SOURCE + swizzled READ
// (16 slots/row XOR row&15, R11-proven).
// Epilogue: 2-round LDS f32 kg-reduction, then fused bias+spline expand.
// NREG==3: K'=3*K regions hh/hl/lh (split-precision bf16x3, K=1024).
template <int NREG, int MQ, int NQ, bool EXPAND>
__global__ __launch_bounds__(512) void gemmS(
    const u16* __restrict__ A0, const u16* __restrict__ A1,
    const u16* __restrict__ B0, const u16* __restrict__ B1,
    const float* __restrict__ bias, const float* __restrict__ grid,
    void* __restrict__ outv, int M, int N, int K, int nsteps) {
  constexpr int BM = MQ * 32, BN = NQ * 32;
  constexpr int ASZ = BM * 128;          // u16
  constexpr int BUF_U16 = (BM + BN) * 128;  // 24 KB
  __shared__ __align__(16) u16 smu[3 * BUF_U16];  // 72 KB -> 2 blocks/CU

  const int tid = threadIdx.x;
  const int lane = tid & 63;
  const int wid = tid >> 6;
  const int mq = (MQ == 2) ? (wid & 1) : 0;
  const int nq = (NQ == 2) ? (wid & 1) : 0;
  const int kg = wid >> 1;  // 0..3

  // XCD-aware swizzle (grid sizes are multiples of 8)
  const int nb = N / BN;
  const int nwg = (M / BM) * nb;
  const int bid = blockIdx.x;
  const int swz = (bid & 7) * (nwg >> 3) + (bid >> 3);
  const int tm = (swz / nb) * BM;
  const int tn = (swz % nb) * BN;

  const u16* pA0 = A0 + (size_t)tm * K;
  const u16* pB0 = B0 + (size_t)tn * K;
  const u16* pA1 = (NREG == 3) ? A1 + (size_t)tm * K : nullptr;
  const u16* pB1 = (NREG == 3) ? B1 + (size_t)tn * K : nullptr;

  // 3 chunks/thread: c = tid + k*512, k=0..2.  c < BM*16 -> A row c>>4;
  // else B row (c-BM*16)>>4.  slot=c&15 sources k-group slot^(row&15).
  int srcO[3];
  bool isA[3];
#pragma unroll
  for (int k = 0; k < 3; ++k) {
    int c = tid + k * 512;
    bool a = c < BM * 16;
    int r = a ? (c >> 4) : ((c - BM * 16) >> 4);
    int sl = c & 15;
    isA[k] = a;
    srcO[k] = r * K + (((sl ^ (r & 15)) & 15) << 3);  // u16 units
  }

  const int lr = lane & 31;
  const int khf = lane >> 5;

  // swizzled LDS read offsets (u16): row*128 + ((slot^(row&15))&15)*8,
  // slot = slice*2 + khf, slice = kg*2 + s
  int offA[2], offB[2];
#pragma unroll
  for (int s = 0; s < 2; ++s) {
    int slice = kg * 2 + s;
    int rowA = mq * 32 + lr;
    int rowB = nq * 32 + lr;
    offA[s] = rowA * 128 + ((((slice * 2 + khf) ^ (rowA & 15)) & 15) << 3);
    offB[s] = rowB * 128 + ((((slice * 2 + khf) ^ (rowB & 15)) & 15) << 3);
  }

  auto stage = [&](int buf, int step) {
    int kk;
    const u16 *Ab, *Bb;
    if constexpr (NREG == 3) {
      int reg = step >> 3;  // K=1024 -> 8 BK-128 steps per region
      kk = (step & 7) << 7;
      Ab = (reg == 2) ? pA1 : pA0;
      Bb = (reg == 1) ? pB1 : pB0;
    } else {
      kk = step << 7;
      Ab = pA0;
      Bb = pB0;
    }
    u16* sb = smu + buf * BUF_U16;
#pragma unroll
    for (int k = 0; k < 3; ++k)
      gload16((isA[k] ? Ab : Bb) + srcO[k] + kk, sb + (k * 512 + wid * 64) * 8);
  };

  f32x16 acc0 = {}, acc1 = {};
  stage(0, 0);
  stage(1, 1);
  int cur = 0, b3 = 2;
  for (int i = 0; i < nsteps; ++i) {
    if (i + 1 < nsteps) vmwait<3>();  // my buf-cur loads landed (next-stage 3 still out)
    else vmwait<0>();
    __builtin_amdgcn_sched_barrier(0);
    __builtin_amdgcn_s_barrier();  // all waves' buf-cur loads landed; step-(i-1) readers done
    __builtin_amdgcn_sched_barrier(0);
    if (i + 2 < nsteps) stage(b3, i + 2);  // safe: b3's readers ran at step i-1

    const u16* sb = smu + cur * BUF_U16;
    bf16x8 af[2], bfr[2];
#pragma unroll
    for (int s = 0; s < 2; ++s) {
      af[s] = *(const bf16x8*)(sb + offA[s]);
      bfr[s] = *(const bf16x8*)(sb + ASZ + offB[s]);
    }
    acc0 = __builtin_amdgcn_mfma_f32_32x32x16_bf16(af[0], bfr[0], acc0, 0, 0, 0);
    acc1 = __builtin_amdgcn_mfma_f32_32x32x16_bf16(af[1], bfr[1], acc1, 0, 0, 0);

    cur = (cur == 2) ? 0 : cur + 1;
    b3 = (b3 == 2) ? 0 : b3 + 1;
  }
  f32x16 accv = acc0 + acc1;

  // C/D layout (m74/m101): col = lane&31, row = (r&3) + 8*(r>>2) + 4*(lane>>5)
  const int rbase = 4 * khf;
  const int rowq = mq * 32, colq = nq * 32;

  // 2-round cross-kg reduction via LDS f32 (kg2/kg3 -> kg0/kg1, then kg1 -> kg0)
  float* Fr = (float*)smu;
  __syncthreads();
  if (kg >= 2) {
#pragma unroll
    for (int r = 0; r < 16; ++r) {
      int row = rowq + rbase + (r & 3) + 8 * (r >> 2);
      Fr[(kg - 2) * (BM * BN) + row * BN + colq + lr] = accv[r];
    }
  }
  __syncthreads();
  if (kg < 2) {
#pragma unroll
    for (int r = 0; r < 16; ++r) {
      int row = rowq + rbase + (r & 3) + 8 * (r >> 2);
      accv[r] += Fr[kg * (BM * BN) + row * BN + colq + lr];
    }
  }
  __syncthreads();
  if (kg == 1) {
#pragma unroll
    for (int r = 0; r < 16; ++r) {
      int row = rowq + rbase + (r & 3) + 8 * (r >> 2);
      Fr[row * BN + colq + lr] = accv[r];
    }
  }
  __syncthreads();
  if (kg == 0) {
#pragma unroll
    for (int r = 0; r < 16; ++r) {
      int row = rowq + rbase + (r & 3) + 8 * (r >> 2);
      accv[r] += Fr[row * BN + colq + lr];
    }
  }

  if constexpr (EXPAND) {
    Spl sp;
    spl_init(grid, sp);
    __syncthreads();  // Fr reads done before F-tile overwrite
    u16* Fl = smu;
    if (kg == 0) {
      int col = colq + lr;
      float bv = bias ? bias[tn + col] : 0.0f;
#pragma unroll
      for (int r = 0; r < 16; ++r) {
        int row = rowq + rbase + (r & 3) + 8 * (r >> 2);
        expand_one(accv[r] + bv, sp, Fl + (size_t)row * (BN * 9) + col * 9);
      }
    }
    __syncthreads();
    // coalesced copy-out: BM x (BN*9) bf16 in 16B chunks, all 512 threads
    u16* Fout = (u16*)outv;
    constexpr int RB = BN * 9 / 8;   // 16B chunks per row
    constexpr int CH = BM * RB;
    const size_t fstride = (size_t)N * 9;
    for (int ch = tid; ch < CH; ch += 512) {
      int r = ch / RB, o = ch - r * RB;
      *(u16x8*)(Fout + (size_t)(tm + r) * fstride + (size_t)tn * 9 + o * 8) =
          *(const u16x8*)(Fl + (size_t)ch * 8);
    }
  } else {
    if (kg == 0) {
      float* Cp = (float*)outv;
      const int cbase = tn + colq + lr;
#pragma unroll
      for (int r = 0; r < 16; ++r) {
        int row = tm + rowq + rbase + (r & 3) + 8 * (r >> 2);
        Cp[(size_t)row * N + cbase] = accv[r];
      }
    }
  }
}

extern "C" void kernel_launch(void* const* d_in, const int* in_sizes, int n_in,
                              void* d_out, int out_size, void* d_ws, size_t ws_size,
                              hipStream_t stream) {
  (void)in_sizes; (void)n_in; (void)out_size; (void)ws_size;
  const float* x     = (const float*)d_in[0];   // 4096x1024
  const float* W1    = (const float*)d_in[1];   // 256x1024
  const float* b1    = (const float*)d_in[2];   // 256
  const float* grid1 = (const float*)d_in[3];   // 256x12 (rows identical)
  const float* coef1 = (const float*)d_in[4];   // 256x256x8
  const float* sb1   = (const float*)d_in[5];
  const float* sp1   = (const float*)d_in[6];
  const float* mask1 = (const float*)d_in[7];
  const float* grid2 = (const float*)d_in[8];
  const float* coef2 = (const float*)d_in[9];   // 256x128x8
  const float* sb2   = (const float*)d_in[10];
  const float* sp2   = (const float*)d_in[11];
  const float* mask2 = (const float*)d_in[12];
  float* outp = (float*)d_out;

  char* ws = (char*)d_ws;
  size_t off = 0;
  auto alloc = [&](size_t bytes) {
    char* p = ws + off;
    off += (bytes + 255) & ~(size_t)255;
    return (void*)p;
  };
  u16* xs_hi  = (u16*)alloc((size_t)4096 * 1024 * 2);
  u16* xs_lo  = (u16*)alloc((size_t)4096 * 1024 * 2);
  u16* w1_hi  = (u16*)alloc((size_t)256 * 1024 * 2);
  u16* w1_lo  = (u16*)alloc((size_t)256 * 1024 * 2);
  u16* wc1    = (u16*)alloc((size_t)256 * K2L * 2);
  u16* wc2    = (u16*)alloc((size_t)128 * K2L * 2);
  u16* F1     = (u16*)alloc((size_t)4096 * K2L * 2);
  u16* F2     = (u16*)alloc((size_t)4096 * K2L * 2);

  // merged prep
  prep_kernel<<<7808, 256, 0, stream>>>(x, W1, coef1, sb1, sp1, mask1,
                                        coef2, sb2, sp2, mask2,
                                        xs_hi, xs_lo, w1_hi, w1_lo, wc1, wc2);

  // L1: F1 = expand(x @ W1^T + b1); bf16x3 K'=3072; BM=64 BN=32; grid 512 (2 blk/CU)
  gemmS<3, 2, 1, true><<<512, 512, 0, stream>>>(
      xs_hi, xs_lo, w1_hi, w1_lo, b1, grid1, F1, 4096, 256, 1024, 24);

  // L2: F2 = expand(F1 @ Wc1^T); K=2304; BM=64 BN=32; grid 512 (2 blk/CU)
  gemmS<1, 2, 1, true><<<512, 512, 0, stream>>>(
      F1, nullptr, wc1, nullptr, nullptr, grid2, F2, 4096, 256, 2304, 18);

  // L3: out = F2 @ Wc2^T; K=2304 N=128; BM=32 BN=64; grid 256 (full machine)
  gemmS<1, 1, 2, false><<<256, 512, 0, stream>>>(
      F2, nullptr, wc2, nullptr, nullptr, nullptr, outp, 4096, 128, 2304, 18);
}

// Round 14
// 62.061 us; speedup vs baseline: 1.2263x; 1.2263x over previous
//
#include <hip/hip_runtime.h>
#include <math.h>

typedef unsigned short u16;
typedef u16 u16x4 __attribute__((ext_vector_type(4)));
typedef u16 u16x8 __attribute__((ext_vector_type(8)));
typedef float f32x4 __attribute__((ext_vector_type(4)));
typedef float f32x16 __attribute__((ext_vector_type(16)));
typedef __bf16 bf16x8 __attribute__((ext_vector_type(8)));

#define KC 8
#define K2L 2304  // 256*9

__device__ __forceinline__ u16 f2bf_rne(float f) {
  unsigned u = __float_as_uint(f);
  u += 0x7FFFu + ((u >> 16) & 1u);
  return (u16)(u >> 16);
}
__device__ __forceinline__ float bf2f(u16 h) {
  return __uint_as_float(((unsigned)h) << 16);
}

// async global->LDS, 16B/lane; LDS dest is the WAVE-UNIFORM base (HW adds lane*16)
__device__ __forceinline__ void gload16(const u16* g, u16* l) {
  __builtin_amdgcn_global_load_lds(
      (const __attribute__((address_space(1))) unsigned*)g,
      (__attribute__((address_space(3))) unsigned*)l, 16, 0, 0);
}
template <int N>
__device__ __forceinline__ void vmwait() {
  if constexpr (N == 0)      asm volatile("s_waitcnt vmcnt(0)" ::: "memory");
  else if constexpr (N == 3) asm volatile("s_waitcnt vmcnt(3)" ::: "memory");
  else if constexpr (N == 4) asm volatile("s_waitcnt vmcnt(4)" ::: "memory");
  else if constexpr (N == 6) asm volatile("s_waitcnt vmcnt(6)" ::: "memory");
  else if constexpr (N == 8) asm volatile("s_waitcnt vmcnt(8)" ::: "memory");
  else static_assert(N == 0, "unsupported vmcnt literal");
}

// ---- merged prep: split x (hi only), split W1 (hi+lo), build Wc1, Wc2 ----
__device__ __forceinline__ void split4(const float* X, u16* hi, u16* lo, int i) {
  f32x4 v = ((const f32x4*)X)[i];
  u16x4 h, l;
#pragma unroll
  for (int c = 0; c < 4; ++c) {
    u16 hb = f2bf_rne(v[c]);
    h[c] = hb;
    l[c] = f2bf_rne(v[c] - bf2f(hb));
  }
  ((u16x4*)hi)[i] = h;
  ((u16x4*)lo)[i] = l;
}
__device__ __forceinline__ void split4hi(const float* X, u16* hi, int i) {
  f32x4 v = ((const f32x4*)X)[i];
  u16x4 h;
#pragma unroll
  for (int c = 0; c < 4; ++c) h[c] = f2bf_rne(v[c]);
  ((u16x4*)hi)[i] = h;
}
__device__ __forceinline__ void wc_one(const float* coef, const float* sb, const float* sp,
                                       const float* mask, u16* W, int N, int idx) {
  int o = idx / K2L;
  int r = idx - o * K2L;
  int i = r / 9;
  int c = r - i * 9;
  int io = i * N + o;
  float m = mask[io];
  float v = (c == 0) ? m * sb[io] : m * sp[io] * coef[(size_t)io * KC + (c - 1)];
  W[idx] = f2bf_rne(v);
}

__global__ void prep_kernel(const float* __restrict__ x, const float* __restrict__ W1,
                            const float* __restrict__ coef1, const float* __restrict__ sb1,
                            const float* __restrict__ sp1, const float* __restrict__ mask1,
                            const float* __restrict__ coef2, const float* __restrict__ sb2,
                            const float* __restrict__ sp2, const float* __restrict__ mask2,
                            u16* __restrict__ xs_hi,
                            u16* __restrict__ w1_hi, u16* __restrict__ w1_lo,
                            u16* __restrict__ wc1, u16* __restrict__ wc2) {
  const int b = blockIdx.x, tid = threadIdx.x;
  if (b < 4096) {
    split4hi(x, xs_hi, b * 256 + tid);  // lo plane unused (NREG=2 scheme)
  } else if (b < 4096 + 256) {
    split4(W1, w1_hi, w1_lo, (b - 4096) * 256 + tid);
  } else if (b < 4096 + 256 + 2304) {
    wc_one(coef1, sb1, sp1, mask1, wc1, 256, (b - 4352) * 256 + tid);
  } else {
    wc_one(coef2, sb2, sp2, mask2, wc2, 128, (b - 6656) * 256 + tid);
  }
}

// ---- spline tables + divide-free expand ----
struct Spl {
  float g[12];
  float d1[11], d2[10], d3[9];
};
__device__ __forceinline__ void spl_init(const float* __restrict__ grid, Spl& sp) {
#pragma unroll
  for (int j = 0; j < 12; ++j) sp.g[j] = grid[j];
#pragma unroll
  for (int j = 0; j < 11; ++j) sp.d1[j] = 1.0f / (sp.g[j + 1] - sp.g[j]);
#pragma unroll
  for (int j = 0; j < 10; ++j) sp.d2[j] = 1.0f / (sp.g[j + 2] - sp.g[j]);
#pragma unroll
  for (int j = 0; j < 9; ++j) sp.d3[j] = 1.0f / (sp.g[j + 3] - sp.g[j]);
}
__device__ __forceinline__ void expand_one(float v, const Spl& sp, u16* dst) {
  float Bv[11];
#pragma unroll
  for (int j = 0; j < 11; ++j) Bv[j] = (v >= sp.g[j] && v < sp.g[j + 1]) ? 1.0f : 0.0f;
#pragma unroll
  for (int j = 0; j < 10; ++j)
    Bv[j] = (v - sp.g[j]) * sp.d1[j] * Bv[j] + (sp.g[j + 2] - v) * sp.d1[j + 1] * Bv[j + 1];
#pragma unroll
  for (int j = 0; j < 9; ++j)
    Bv[j] = (v - sp.g[j]) * sp.d2[j] * Bv[j] + (sp.g[j + 3] - v) * sp.d2[j + 1] * Bv[j + 1];
#pragma unroll
  for (int j = 0; j < 8; ++j)
    Bv[j] = (v - sp.g[j]) * sp.d3[j] * Bv[j] + (sp.g[j + 4] - v) * sp.d3[j + 1] * Bv[j + 1];
  dst[0] = f2bf_rne(v / (1.0f + __expf(-v)));  // silu
#pragma unroll
  for (int k = 0; k < 8; ++k) dst[1 + k] = f2bf_rne(Bv[k]);
}

// ---- 8-wave MFMA GEMM (R11-proven pipeline, geometry-templated) ----
// BM=MQ*32, BN=NQ*32; 8 waves = (MQ*NQ) spatial quadrants x KG K-groups.
// BK=128 (8 K-16 slices/step; each kg owns 8/KG).  4-buf ring, depth-2
// prefetch, counted vmcnt, ONE s_barrier/step, stage BEFORE vmwait (R11).
// Staging: linear LDS dest + inverse-swizzled global SOURCE + swizzled READ
// (16 slots/row XOR row&15).
// Epilogue: LDS f32 kg-reduction (1 round KG=2, 2 rounds KG=4), then fused
// bias+spline expand (EXPAND) or f32 C-write.
// NREG==2: K'=2*K regions (A0,B0),(A0,B1) == x_hi*(W_hi+W_lo).
template <int NREG, int MQ, int NQ, int KG, bool EXPAND>
__global__ __launch_bounds__(512) void gemmW(
    const u16* __restrict__ A0, const u16* __restrict__ B0, const u16* __restrict__ B1,
    const float* __restrict__ bias, const float* __restrict__ grid,
    void* __restrict__ outv, int M, int N, int K, int nsteps) {
  static_assert(MQ * NQ * KG == 8, "8 waves");
  constexpr int BM = MQ * 32, BN = NQ * 32;
  constexpr int ASZ = BM * 128;              // u16
  constexpr int BUF_U16 = (BM + BN) * 128;
  constexpr int NCH = (BM + BN) * 16;        // 16B chunks per tile
  constexpr int LPT = NCH / 512;             // gloads per thread per stage
  constexpr int SPK = 8 / KG;                // K-16 slices per kg
  __shared__ __align__(16) u16 smu[4 * BUF_U16];

  const int tid = threadIdx.x;
  const int lane = tid & 63;
  const int wid = tid >> 6;
  const int q = wid % (MQ * NQ);
  const int kg = wid / (MQ * NQ);
  const int mq = (NQ == 2) ? (q >> 1) : q;
  const int nq = (NQ == 2) ? (q & 1) : 0;

  // XCD-aware swizzle (grid sizes are multiples of 8)
  const int nb = N / BN;
  const int nwg = (M / BM) * nb;
  const int bid = blockIdx.x;
  const int swz = (bid & 7) * (nwg >> 3) + (bid >> 3);
  const int tm = (swz / nb) * BM;
  const int tn = (swz % nb) * BN;

  const u16* pA0 = A0 + (size_t)tm * K;
  const u16* pB0 = B0 + (size_t)tn * K;
  const u16* pB1 = (NREG == 2) ? B1 + (size_t)tn * K : nullptr;

  // chunk c: A if c < BM*16 (row c>>4) else B (row (c-BM*16)>>4); slot=c&15
  // sources k-group slot^(row&15).  LDS linear dest offset = c*16B.
  int srcO[LPT];
  bool isA[LPT];
#pragma unroll
  for (int k = 0; k < LPT; ++k) {
    int c = tid + k * 512;
    bool a = c < BM * 16;
    int r = a ? (c >> 4) : ((c - BM * 16) >> 4);
    int sl = c & 15;
    isA[k] = a;
    srcO[k] = r * K + (((sl ^ (r & 15)) & 15) << 3);  // u16 units
  }

  const int lr = lane & 31;
  const int khf = lane >> 5;

  // swizzled LDS read offsets (u16): row*128 + ((slot^(row&15))&15)*8,
  // slot = slice*2 + khf, slice = kg*SPK + s
  int offA[SPK], offB[SPK];
#pragma unroll
  for (int s = 0; s < SPK; ++s) {
    int slice = kg * SPK + s;
    int rowA = mq * 32 + lr;
    int rowB = nq * 32 + lr;
    offA[s] = rowA * 128 + ((((slice * 2 + khf) ^ (rowA & 15)) & 15) << 3);
    offB[s] = rowB * 128 + ((((slice * 2 + khf) ^ (rowB & 15)) & 15) << 3);
  }

  auto stage = [&](int buf, int step) {
    int kk;
    const u16 *Ab, *Bb;
    if constexpr (NREG == 2) {
      int reg = step >> 3;  // K=1024 -> 8 BK-128 steps per region
      kk = (step & 7) << 7;
      Ab = pA0;
      Bb = (reg == 1) ? pB1 : pB0;
    } else {
      kk = step << 7;
      Ab = pA0;
      Bb = pB0;
    }
    u16* sb = smu + buf * BUF_U16;
#pragma unroll
    for (int k = 0; k < LPT; ++k)
      gload16((isA[k] ? Ab : Bb) + srcO[k] + kk, sb + (k * 512 + wid * 64) * 8);
  };

  f32x16 acc0 = {}, acc1 = {};
  stage(0, 0);
  stage(1, 1);
  for (int i = 0; i < nsteps; ++i) {
    if (i + 2 < nsteps) {
      stage((i + 2) & 3, i + 2);
      vmwait<2 * LPT>();  // my LPT loads for buf[i&3] landed (2 stages in flight)
    } else if (i + 1 < nsteps) {
      vmwait<LPT>();
    } else {
      vmwait<0>();
    }
    __builtin_amdgcn_sched_barrier(0);
    __builtin_amdgcn_s_barrier();  // everyone's buf-i loads landed;
                                   // also fences reads of buf[(i+2)&3] (iter i-2)
    __builtin_amdgcn_sched_barrier(0);

    const u16* sb = smu + (i & 3) * BUF_U16;
    bf16x8 af[SPK], bfr[SPK];
#pragma unroll
    for (int s = 0; s < SPK; ++s) {
      af[s] = *(const bf16x8*)(sb + offA[s]);
      bfr[s] = *(const bf16x8*)(sb + ASZ + offB[s]);
    }
#pragma unroll
    for (int s = 0; s < SPK; ++s) {
      f32x16& ac = (s & 1) ? acc1 : acc0;  // 2 chains for MFMA ILP
      ac = __builtin_amdgcn_mfma_f32_32x32x16_bf16(af[s], bfr[s], ac, 0, 0, 0);
    }
  }
  f32x16 accv = acc0 + acc1;

  // C/D layout (m74/m101): col = lane&31, row = (r&3) + 8*(r>>2) + 4*(lane>>5)
  const int rbase = 4 * khf;
  const int rowq = mq * 32, colq = nq * 32;

  float* Fr = (float*)smu;
  if constexpr (KG == 2) {
    // 1-round reduction: kg1 -> kg0 (R11-proven)
    __syncthreads();
    if (kg == 1) {
#pragma unroll
      for (int r = 0; r < 16; ++r) {
        int row = rowq + rbase + (r & 3) + 8 * (r >> 2);
        Fr[row * BN + colq + lr] = accv[r];
      }
    }
    __syncthreads();
    if (kg == 0) {
#pragma unroll
      for (int r = 0; r < 16; ++r) {
        int row = rowq + rbase + (r & 3) + 8 * (r >> 2);
        accv[r] += Fr[row * BN + colq + lr];
      }
    }
  } else {
    // 2-round reduction: kg2/kg3 -> kg0/kg1, then kg1 -> kg0 (R12-proven)
    __syncthreads();
    if (kg >= 2) {
#pragma unroll
      for (int r = 0; r < 16; ++r) {
        int row = rowq + rbase + (r & 3) + 8 * (r >> 2);
        Fr[(kg - 2) * (BM * BN) + row * BN + colq + lr] = accv[r];
      }
    }
    __syncthreads();
    if (kg < 2) {
#pragma unroll
      for (int r = 0; r < 16; ++r) {
        int row = rowq + rbase + (r & 3) + 8 * (r >> 2);
        accv[r] += Fr[kg * (BM * BN) + row * BN + colq + lr];
      }
    }
    __syncthreads();
    if (kg == 1) {
#pragma unroll
      for (int r = 0; r < 16; ++r) {
        int row = rowq + rbase + (r & 3) + 8 * (r >> 2);
        Fr[row * BN + colq + lr] = accv[r];
      }
    }
    __syncthreads();
    if (kg == 0) {
#pragma unroll
      for (int r = 0; r < 16; ++r) {
        int row = rowq + rbase + (r & 3) + 8 * (r >> 2);
        accv[r] += Fr[row * BN + colq + lr];
      }
    }
  }

  if constexpr (EXPAND) {
    Spl sp;
    spl_init(grid, sp);
    __syncthreads();  // Fr reads done before F-tile overwrite
    u16* Fl = smu;
    if (kg == 0) {
      int col = colq + lr;
      float bv = bias ? bias[tn + col] : 0.0f;
#pragma unroll
      for (int r = 0; r < 16; ++r) {
        int row = rowq + rbase + (r & 3) + 8 * (r >> 2);
        expand_one(accv[r] + bv, sp, Fl + (size_t)row * (BN * 9) + col * 9);
      }
    }
    __syncthreads();
    // coalesced copy-out: BM x (BN*9) bf16 in 16B chunks, all 512 threads
    u16* Fout = (u16*)outv;
    constexpr int RB = BN * 9 / 8;
    constexpr int CH = BM * RB;
    const size_t fstride = (size_t)N * 9;
    for (int ch = tid; ch < CH; ch += 512) {
      int r = ch / RB, o = ch - r * RB;
      *(u16x8*)(Fout + (size_t)(tm + r) * fstride + (size_t)tn * 9 + o * 8) =
          *(const u16x8*)(Fl + (size_t)ch * 8);
    }
  } else {
    if (kg == 0) {
      float* Cp = (float*)outv;
      const int cbase = tn + colq + lr;
#pragma unroll
      for (int r = 0; r < 16; ++r) {
        int row = tm + rowq + rbase + (r & 3) + 8 * (r >> 2);
        Cp[(size_t)row * N + cbase] = accv[r];
      }
    }
  }
}

extern "C" void kernel_launch(void* const* d_in, const int* in_sizes, int n_in,
                              void* d_out, int out_size, void* d_ws, size_t ws_size,
                              hipStream_t stream) {
  (void)in_sizes; (void)n_in; (void)out_size; (void)ws_size;
  const float* x     = (const float*)d_in[0];   // 4096x1024
  const float* W1    = (const float*)d_in[1];   // 256x1024
  const float* b1    = (const float*)d_in[2];   // 256
  const float* grid1 = (const float*)d_in[3];   // 256x12 (rows identical)
  const float* coef1 = (const float*)d_in[4];   // 256x256x8
  const float* sb1   = (const float*)d_in[5];
  const float* sp1   = (const float*)d_in[6];
  const float* mask1 = (const float*)d_in[7];
  const float* grid2 = (const float*)d_in[8];
  const float* coef2 = (const float*)d_in[9];   // 256x128x8
  const float* sb2   = (const float*)d_in[10];
  const float* sp2   = (const float*)d_in[11];
  const float* mask2 = (const float*)d_in[12];
  float* outp = (float*)d_out;

  char* ws = (char*)d_ws;
  size_t off = 0;
  auto alloc = [&](size_t bytes) {
    char* p = ws + off;
    off += (bytes + 255) & ~(size_t)255;
    return (void*)p;
  };
  u16* xs_hi  = (u16*)alloc((size_t)4096 * 1024 * 2);
  u16* w1_hi  = (u16*)alloc((size_t)256 * 1024 * 2);
  u16* w1_lo  = (u16*)alloc((size_t)256 * 1024 * 2);
  u16* wc1    = (u16*)alloc((size_t)256 * K2L * 2);
  u16* wc2    = (u16*)alloc((size_t)128 * K2L * 2);
  u16* F1     = (u16*)alloc((size_t)4096 * K2L * 2);
  u16* F2     = (u16*)alloc((size_t)4096 * K2L * 2);

  // merged prep (x hi-only split)
  prep_kernel<<<7808, 256, 0, stream>>>(x, W1, coef1, sb1, sp1, mask1,
                                        coef2, sb2, sp2, mask2,
                                        xs_hi, w1_hi, w1_lo, wc1, wc2);

  // L1: F1 = expand(x_hi @ (W1_hi+W1_lo)^T + b1); NREG=2, K'=2048 -> 16 steps
  gemmW<2, 2, 2, 2, true><<<256, 512, 0, stream>>>(
      xs_hi, w1_hi, w1_lo, b1, grid1, F1, 4096, 256, 1024, 16);

  // L2: F2 = expand(F1 @ Wc1^T); K=2304 -> 18 steps; grid 256
  gemmW<1, 2, 2, 2, true><<<256, 512, 0, stream>>>(
      F1, wc1, nullptr, nullptr, grid2, F2, 4096, 256, 2304, 18);

  // L3: out = F2 @ Wc2^T; K=2304, N=128; BM=64 BN=32 -> grid 256 (full machine)
  gemmW<1, 2, 1, 4, false><<<256, 512, 0, stream>>>(
      F2, wc2, nullptr, nullptr, nullptr, outp, 4096, 128, 2304, 18);
}

// Round 15
// 57.383 us; speedup vs baseline: 1.3262x; 1.0815x over previous
//
#include <hip/hip_runtime.h>
#include <math.h>

typedef unsigned short u16;
typedef u16 u16x4 __attribute__((ext_vector_type(4)));
typedef u16 u16x8 __attribute__((ext_vector_type(8)));
typedef float f32x4 __attribute__((ext_vector_type(4)));
typedef float f32x16 __attribute__((ext_vector_type(16)));
typedef __bf16 bf16x8 __attribute__((ext_vector_type(8)));

#define KC 8
#define K2L 2304  // 256*9

__device__ __forceinline__ u16 f2bf_rne(float f) {
  unsigned u = __float_as_uint(f);
  u += 0x7FFFu + ((u >> 16) & 1u);
  return (u16)(u >> 16);
}

// async global->LDS, 16B/lane; LDS dest is the WAVE-UNIFORM base (HW adds lane*16)
__device__ __forceinline__ void gload16(const u16* g, u16* l) {
  __builtin_amdgcn_global_load_lds(
      (const __attribute__((address_space(1))) unsigned*)g,
      (__attribute__((address_space(3))) unsigned*)l, 16, 0, 0);
}
template <int N>
__device__ __forceinline__ void vmwait() {
  if constexpr (N == 0)      asm volatile("s_waitcnt vmcnt(0)" ::: "memory");
  else if constexpr (N == 3) asm volatile("s_waitcnt vmcnt(3)" ::: "memory");
  else if constexpr (N == 4) asm volatile("s_waitcnt vmcnt(4)" ::: "memory");
  else if constexpr (N == 6) asm volatile("s_waitcnt vmcnt(6)" ::: "memory");
  else if constexpr (N == 8) asm volatile("s_waitcnt vmcnt(8)" ::: "memory");
  else static_assert(N == 0, "unsupported vmcnt literal");
}

// ---- merged prep: bf16-cast x, bf16-cast W1, build Wc1, Wc2 ----
__device__ __forceinline__ void split4hi(const float* X, u16* hi, int i) {
  f32x4 v = ((const f32x4*)X)[i];
  u16x4 h;
#pragma unroll
  for (int c = 0; c < 4; ++c) h[c] = f2bf_rne(v[c]);
  ((u16x4*)hi)[i] = h;
}
__device__ __forceinline__ void wc_one(const float* coef, const float* sb, const float* sp,
                                       const float* mask, u16* W, int N, int idx) {
  int o = idx / K2L;
  int r = idx - o * K2L;
  int i = r / 9;
  int c = r - i * 9;
  int io = i * N + o;
  float m = mask[io];
  float v = (c == 0) ? m * sb[io] : m * sp[io] * coef[(size_t)io * KC + (c - 1)];
  W[idx] = f2bf_rne(v);
}

__global__ void prep_kernel(const float* __restrict__ x, const float* __restrict__ W1,
                            const float* __restrict__ coef1, const float* __restrict__ sb1,
                            const float* __restrict__ sp1, const float* __restrict__ mask1,
                            const float* __restrict__ coef2, const float* __restrict__ sb2,
                            const float* __restrict__ sp2, const float* __restrict__ mask2,
                            u16* __restrict__ xs_hi, u16* __restrict__ w1_hi,
                            u16* __restrict__ wc1, u16* __restrict__ wc2) {
  const int b = blockIdx.x, tid = threadIdx.x;
  if (b < 4096) {
    split4hi(x, xs_hi, b * 256 + tid);
  } else if (b < 4096 + 256) {
    split4hi(W1, w1_hi, (b - 4096) * 256 + tid);
  } else if (b < 4096 + 256 + 2304) {
    wc_one(coef1, sb1, sp1, mask1, wc1, 256, (b - 4352) * 256 + tid);
  } else {
    wc_one(coef2, sb2, sp2, mask2, wc2, 128, (b - 6656) * 256 + tid);
  }
}

// ---- spline tables + divide-free expand ----
struct Spl {
  float g[12];
  float d1[11], d2[10], d3[9];
};
__device__ __forceinline__ void spl_init(const float* __restrict__ grid, Spl& sp) {
#pragma unroll
  for (int j = 0; j < 12; ++j) sp.g[j] = grid[j];
#pragma unroll
  for (int j = 0; j < 11; ++j) sp.d1[j] = 1.0f / (sp.g[j + 1] - sp.g[j]);
#pragma unroll
  for (int j = 0; j < 10; ++j) sp.d2[j] = 1.0f / (sp.g[j + 2] - sp.g[j]);
#pragma unroll
  for (int j = 0; j < 9; ++j) sp.d3[j] = 1.0f / (sp.g[j + 3] - sp.g[j]);
}
__device__ __forceinline__ void expand_one(float v, const Spl& sp, u16* dst) {
  float Bv[11];
#pragma unroll
  for (int j = 0; j < 11; ++j) Bv[j] = (v >= sp.g[j] && v < sp.g[j + 1]) ? 1.0f : 0.0f;
#pragma unroll
  for (int j = 0; j < 10; ++j)
    Bv[j] = (v - sp.g[j]) * sp.d1[j] * Bv[j] + (sp.g[j + 2] - v) * sp.d1[j + 1] * Bv[j + 1];
#pragma unroll
  for (int j = 0; j < 9; ++j)
    Bv[j] = (v - sp.g[j]) * sp.d2[j] * Bv[j] + (sp.g[j + 3] - v) * sp.d2[j + 1] * Bv[j + 1];
#pragma unroll
  for (int j = 0; j < 8; ++j)
    Bv[j] = (v - sp.g[j]) * sp.d3[j] * Bv[j] + (sp.g[j + 4] - v) * sp.d3[j + 1] * Bv[j + 1];
  dst[0] = f2bf_rne(v / (1.0f + __expf(-v)));  // silu
#pragma unroll
  for (int k = 0; k < 8; ++k) dst[1 + k] = f2bf_rne(Bv[k]);
}

// ---- 8-wave MFMA GEMM (R11/R14-proven pipeline) ----
// BM=MQ*32, BN=NQ*32; 8 waves = (MQ*NQ) spatial quadrants x KG K-groups.
// BK=128; 4-buf ring, depth-2 prefetch, counted vmcnt, ONE s_barrier/step.
// Staging: linear LDS dest + inverse-swizzled global SOURCE + swizzled READ
// (16 slots/row XOR row&15).
// Epilogue KG=2: SYMMETRIC kg exchange (both add; f32 commutative -> identical
// sums) so BOTH kg groups hold the result, then expand split r<8 / r>=8 across
// kg -> half the serial spline chain.  KG=4: 2-round reduction to kg0.
template <int MQ, int NQ, int KG, bool EXPAND>
__global__ __launch_bounds__(512) void gemmW(
    const u16* __restrict__ A0, const u16* __restrict__ B0,
    const float* __restrict__ bias, const float* __restrict__ grid,
    void* __restrict__ outv, int M, int N, int K, int nsteps) {
  static_assert(MQ * NQ * KG == 8, "8 waves");
  constexpr int BM = MQ * 32, BN = NQ * 32;
  constexpr int ASZ = BM * 128;              // u16
  constexpr int BUF_U16 = (BM + BN) * 128;
  constexpr int LPT = (BM + BN) * 16 / 512;  // gloads per thread per stage
  constexpr int SPK = 8 / KG;                // K-16 slices per kg
  __shared__ __align__(16) u16 smu[4 * BUF_U16];

  const int tid = threadIdx.x;
  const int lane = tid & 63;
  const int wid = tid >> 6;
  const int q = wid % (MQ * NQ);
  const int kg = wid / (MQ * NQ);
  const int mq = (NQ == 2) ? (q >> 1) : q;
  const int nq = (NQ == 2) ? (q & 1) : 0;

  // XCD-aware swizzle (grid sizes are multiples of 8)
  const int nb = N / BN;
  const int nwg = (M / BM) * nb;
  const int bid = blockIdx.x;
  const int swz = (bid & 7) * (nwg >> 3) + (bid >> 3);
  const int tm = (swz / nb) * BM;
  const int tn = (swz % nb) * BN;

  const u16* pA0 = A0 + (size_t)tm * K;
  const u16* pB0 = B0 + (size_t)tn * K;

  // chunk c: A if c < BM*16 (row c>>4) else B (row (c-BM*16)>>4); slot=c&15
  // sources k-group slot^(row&15).  LDS linear dest offset = c*16B.
  int srcO[LPT];
  bool isA[LPT];
#pragma unroll
  for (int k = 0; k < LPT; ++k) {
    int c = tid + k * 512;
    bool a = c < BM * 16;
    int r = a ? (c >> 4) : ((c - BM * 16) >> 4);
    int sl = c & 15;
    isA[k] = a;
    srcO[k] = r * K + (((sl ^ (r & 15)) & 15) << 3);  // u16 units
  }

  const int lr = lane & 31;
  const int khf = lane >> 5;

  // swizzled LDS read offsets (u16): row*128 + ((slot^(row&15))&15)*8,
  // slot = slice*2 + khf, slice = kg*SPK + s
  int offA[SPK], offB[SPK];
#pragma unroll
  for (int s = 0; s < SPK; ++s) {
    int slice = kg * SPK + s;
    int rowA = mq * 32 + lr;
    int rowB = nq * 32 + lr;
    offA[s] = rowA * 128 + ((((slice * 2 + khf) ^ (rowA & 15)) & 15) << 3);
    offB[s] = rowB * 128 + ((((slice * 2 + khf) ^ (rowB & 15)) & 15) << 3);
  }

  auto stage = [&](int buf, int step) {
    int kk = step << 7;
    u16* sb = smu + buf * BUF_U16;
#pragma unroll
    for (int k = 0; k < LPT; ++k)
      gload16((isA[k] ? pA0 : pB0) + srcO[k] + kk, sb + (k * 512 + wid * 64) * 8);
  };

  f32x16 acc0 = {}, acc1 = {};
  stage(0, 0);
  stage(1, 1);
  for (int i = 0; i < nsteps; ++i) {
    if (i + 2 < nsteps) {
      stage((i + 2) & 3, i + 2);
      vmwait<2 * LPT>();  // my LPT loads for buf[i&3] landed (2 stages in flight)
    } else if (i + 1 < nsteps) {
      vmwait<LPT>();
    } else {
      vmwait<0>();
    }
    __builtin_amdgcn_sched_barrier(0);
    __builtin_amdgcn_s_barrier();  // everyone's buf-i loads landed;
                                   // also fences reads of buf[(i+2)&3] (iter i-2)
    __builtin_amdgcn_sched_barrier(0);

    const u16* sb = smu + (i & 3) * BUF_U16;
    bf16x8 af[SPK], bfr[SPK];
#pragma unroll
    for (int s = 0; s < SPK; ++s) {
      af[s] = *(const bf16x8*)(sb + offA[s]);
      bfr[s] = *(const bf16x8*)(sb + ASZ + offB[s]);
    }
#pragma unroll
    for (int s = 0; s < SPK; ++s) {
      f32x16& ac = (s & 1) ? acc1 : acc0;  // 2 chains for MFMA ILP
      ac = __builtin_amdgcn_mfma_f32_32x32x16_bf16(af[s], bfr[s], ac, 0, 0, 0);
    }
  }
  f32x16 accv = acc0 + acc1;

  // C/D layout (m74/m101): col = lane&31, row = (r&3) + 8*(r>>2) + 4*(lane>>5)
  const int rbase = 4 * khf;
  const int rowq = mq * 32, colq = nq * 32;

  float* Fr = (float*)smu;
  if constexpr (KG == 2) {
    // symmetric exchange: both kgs end up with the full sum (f32 + commutative)
    __syncthreads();
#pragma unroll
    for (int r = 0; r < 16; ++r) {
      int row = rowq + rbase + (r & 3) + 8 * (r >> 2);
      Fr[kg * (BM * BN) + row * BN + colq + lr] = accv[r];
    }
    __syncthreads();
#pragma unroll
    for (int r = 0; r < 16; ++r) {
      int row = rowq + rbase + (r & 3) + 8 * (r >> 2);
      accv[r] += Fr[(1 - kg) * (BM * BN) + row * BN + colq + lr];
    }
  } else {
    // 2-round reduction to kg0 (R12-proven)
    __syncthreads();
    if (kg >= 2) {
#pragma unroll
      for (int r = 0; r < 16; ++r) {
        int row = rowq + rbase + (r & 3) + 8 * (r >> 2);
        Fr[(kg - 2) * (BM * BN) + row * BN + colq + lr] = accv[r];
      }
    }
    __syncthreads();
    if (kg < 2) {
#pragma unroll
      for (int r = 0; r < 16; ++r) {
        int row = rowq + rbase + (r & 3) + 8 * (r >> 2);
        accv[r] += Fr[kg * (BM * BN) + row * BN + colq + lr];
      }
    }
    __syncthreads();
    if (kg == 1) {
#pragma unroll
      for (int r = 0; r < 16; ++r) {
        int row = rowq + rbase + (r & 3) + 8 * (r >> 2);
        Fr[row * BN + colq + lr] = accv[r];
      }
    }
    __syncthreads();
    if (kg == 0) {
#pragma unroll
      for (int r = 0; r < 16; ++r) {
        int row = rowq + rbase + (r & 3) + 8 * (r >> 2);
        accv[r] += Fr[row * BN + colq + lr];
      }
    }
  }

  if constexpr (EXPAND) {
    Spl sp;
    spl_init(grid, sp);
    __syncthreads();  // Fr reads done before F-tile overwrite
    u16* Fl = smu;
    {
      int col = colq + lr;
      float bv = bias ? bias[tn + col] : 0.0f;
      // split the serial spline chain across kg: kg0 -> r<8, kg1 -> r>=8
      const int r0 = kg * 8, r1 = r0 + 8;
#pragma unroll
      for (int r = 0; r < 16; ++r) {
        if (r >= r0 && r < r1) {
          int row = rowq + rbase + (r & 3) + 8 * (r >> 2);
          expand_one(accv[r] + bv, sp, Fl + (size_t)row * (BN * 9) + col * 9);
        }
      }
    }
    __syncthreads();
    // coalesced copy-out: BM x (BN*9) bf16 in 16B chunks, all 512 threads
    u16* Fout = (u16*)outv;
    constexpr int RB = BN * 9 / 8;
    constexpr int CH = BM * RB;
    const size_t fstride = (size_t)N * 9;
    for (int ch = tid; ch < CH; ch += 512) {
      int r = ch / RB, o = ch - r * RB;
      *(u16x8*)(Fout + (size_t)(tm + r) * fstride + (size_t)tn * 9 + o * 8) =
          *(const u16x8*)(Fl + (size_t)ch * 8);
    }
  } else {
    if (kg == 0) {
      float* Cp = (float*)outv;
      const int cbase = tn + colq + lr;
#pragma unroll
      for (int r = 0; r < 16; ++r) {
        int row = tm + rowq + rbase + (r & 3) + 8 * (r >> 2);
        Cp[(size_t)row * N + cbase] = accv[r];
      }
    }
  }
}

extern "C" void kernel_launch(void* const* d_in, const int* in_sizes, int n_in,
                              void* d_out, int out_size, void* d_ws, size_t ws_size,
                              hipStream_t stream) {
  (void)in_sizes; (void)n_in; (void)out_size; (void)ws_size;
  const float* x     = (const float*)d_in[0];   // 4096x1024
  const float* W1    = (const float*)d_in[1];   // 256x1024
  const float* b1    = (const float*)d_in[2];   // 256
  const float* grid1 = (const float*)d_in[3];   // 256x12 (rows identical)
  const float* coef1 = (const float*)d_in[4];   // 256x256x8
  const float* sb1   = (const float*)d_in[5];
  const float* sp1   = (const float*)d_in[6];
  const float* mask1 = (const float*)d_in[7];
  const float* grid2 = (const float*)d_in[8];
  const float* coef2 = (const float*)d_in[9];   // 256x128x8
  const float* sb2   = (const float*)d_in[10];
  const float* sp2   = (const float*)d_in[11];
  const float* mask2 = (const float*)d_in[12];
  float* outp = (float*)d_out;

  char* ws = (char*)d_ws;
  size_t off = 0;
  auto alloc = [&](size_t bytes) {
    char* p = ws + off;
    off += (bytes + 255) & ~(size_t)255;
    return (void*)p;
  };
  u16* xs_hi  = (u16*)alloc((size_t)4096 * 1024 * 2);
  u16* w1_hi  = (u16*)alloc((size_t)256 * 1024 * 2);
  u16* wc1    = (u16*)alloc((size_t)256 * K2L * 2);
  u16* wc2    = (u16*)alloc((size_t)128 * K2L * 2);
  u16* F1     = (u16*)alloc((size_t)4096 * K2L * 2);
  u16* F2     = (u16*)alloc((size_t)4096 * K2L * 2);

  // merged prep (all bf16 casts + Wc builds)
  prep_kernel<<<7808, 256, 0, stream>>>(x, W1, coef1, sb1, sp1, mask1,
                                        coef2, sb2, sp2, mask2,
                                        xs_hi, w1_hi, wc1, wc2);

  // L1: F1 = expand(x_bf @ W1_bf^T + b1); K=1024 -> 8 steps; grid 256
  gemmW<2, 2, 2, true><<<256, 512, 0, stream>>>(
      xs_hi, w1_hi, b1, grid1, F1, 4096, 256, 1024, 8);

  // L2: F2 = expand(F1 @ Wc1^T); K=2304 -> 18 steps; grid 256
  gemmW<2, 2, 2, true><<<256, 512, 0, stream>>>(
      F1, wc1, nullptr, grid2, F2, 4096, 256, 2304, 18);

  // L3: out = F2 @ Wc2^T; K=2304, N=128; BM=64 BN=32 -> grid 256
  gemmW<2, 1, 4, false><<<256, 512, 0, stream>>>(
      F2, wc2, nullptr, nullptr, outp, 4096, 128, 2304, 18);
}